// Round 1
// baseline (2080.895 us; speedup 1.0000x reference)
//
#include <hip/hip_runtime.h>
#include <math.h>

#define N_SETS 4096
#define MAXN   64
#define DIM    256
#define WDIM   32

// ---------------- ws layout ----------------
// pe:    [64][256] f32   @ 0        (65536 B)
// query: [64][32]  f32   @ 65536    (8192 B)
// ptr:   [4097]    i32   @ 73728    (16388 B)
#define WS_PE    0
#define WS_QUERY 65536
#define WS_PTR   73728

// Set-start detection + batch echo (output 1, written as float values)
__global__ void k_batch_ptr(const int* __restrict__ batch, float* __restrict__ out2,
                            int* __restrict__ ptr, int N) {
    int i = blockIdx.x * blockDim.x + threadIdx.x;
    if (i >= N) return;
    int b = batch[i];
    out2[i] = (float)b;
    if (i == 0 || batch[i - 1] != b) ptr[b] = i;
    if (i == N - 1) ptr[N_SETS] = N;
}

// sinusoid PE table [64][256]
__global__ void k_pe(float* __restrict__ pe) {
    int idx = blockIdx.x * blockDim.x + threadIdx.x;   // 0..16383
    int p = idx >> 8, i = idx & 255;
    float e   = (float)(2 * (i / 2)) / 256.0f;
    float inv = powf(10000.0f, -e);
    float ang = (float)p * inv;
    pe[idx] = (i & 1) ? cosf(ang) : sinf(ang);
}

// query[m][k] = sum_d pe[m][d] * Wq[k][d]   (64x32)
__global__ void k_query(const float* __restrict__ pe, const float* __restrict__ Wq,
                        float* __restrict__ query) {
    int idx = blockIdx.x * blockDim.x + threadIdx.x;   // 0..2047
    int m = idx >> 5, k = idx & 31;
    float s = 0.f;
    const float* pr = pe + m * 256;
    const float* wr = Wq + k * 256;
    for (int d = 0; d < 256; d += 4) {
        float4 a = *(const float4*)&pr[d];
        float4 b = *(const float4*)&wr[d];
        s += a.x * b.x + a.y * b.y + a.z * b.z + a.w * b.w;
    }
    query[idx] = s;
}

// Fused encoder+decoder: one workgroup per set.
__global__ __launch_bounds__(256) void k_main(
        const float* __restrict__ x,    const float* __restrict__ Wk,
        const float* __restrict__ Wv,   const float* __restrict__ Wmap,
        const float* __restrict__ bmap, const float* __restrict__ pe,
        const float* __restrict__ query, const int* __restrict__ ptr,
        float* __restrict__ out) {
    __shared__ float z_sh[32][33];       // +1 pad: conflict-free col reads
    __shared__ float ysh[2][2][32];      // [parity][k/v][w]
    __shared__ float dec_sh[2][32];      // [parity][v]
    __shared__ float qsh[64][32];

    const int b = blockIdx.x;
    const int t = threadIdx.x;
    const int s = ptr[b], e = ptr[b + 1];
    const int w = t >> 3, part = t & 7;  // 32 outputs x 8 K-slices
    const int irow = t >> 5;             // z rows owned: irow*4 .. +3
    const int jcol = t & 31;             // z col owned

    // stage query table
    for (int i = t; i < 64 * 32; i += 256) ((float*)qsh)[i] = query[i];

    // per-thread weight slices in registers
    float wk[32], wv[32], wm[32];
    {
        const float* wkp = Wk + w * 256 + part * 32;
        const float* wvp = Wv + w * 256 + part * 32;
        #pragma unroll
        for (int j = 0; j < 32; j += 4) {
            *(float4*)&wk[j] = *(const float4*)&wkp[j];
            *(float4*)&wv[j] = *(const float4*)&wvp[j];
        }
        const float* wmp = Wmap + t * 32;
        #pragma unroll
        for (int j = 0; j < 32; j += 4) *(float4*)&wm[j] = *(const float4*)&wmp[j];
    }
    const float bm = bmap[t];

    float zacc[4] = {0.f, 0.f, 0.f, 0.f};

    // ---------------- encoder: z[b] = sum_rows yv (x) yk ----------------
    for (int r = s; r < e; ++r) {
        const int pos = r - s;
        const float* xr  = x  + (size_t)r * 256 + part * 32;
        const float* per = pe + (size_t)pos * 256 + part * 32;
        float pk = 0.f, pv = 0.f;
        #pragma unroll
        for (int q = 0; q < 32; q += 4) {
            float4 xv = *(const float4*)&xr[q];
            float4 pp = *(const float4*)&per[q];
            float h0 = xv.x + pp.x, h1 = xv.y + pp.y;
            float h2 = xv.z + pp.z, h3 = xv.w + pp.w;
            pk += h0 * wk[q] + h1 * wk[q + 1] + h2 * wk[q + 2] + h3 * wk[q + 3];
            pv += h0 * wv[q] + h1 * wv[q + 1] + h2 * wv[q + 2] + h3 * wv[q + 3];
        }
        pk += __shfl_xor(pk, 1); pk += __shfl_xor(pk, 2); pk += __shfl_xor(pk, 4);
        pv += __shfl_xor(pv, 1); pv += __shfl_xor(pv, 2); pv += __shfl_xor(pv, 4);
        const int par = r & 1;
        if (part == 0) { ysh[par][0][w] = pk; ysh[par][1][w] = pv; }
        __syncthreads();
        const float yk0 = ysh[par][0][jcol];
        #pragma unroll
        for (int k = 0; k < 4; ++k) zacc[k] += ysh[par][1][irow * 4 + k] * yk0;
        // next row writes the other parity buffer; row r+2's write is fenced
        // by row r+1's barrier -> no extra barrier needed here
    }

    __syncthreads();
    #pragma unroll
    for (int k = 0; k < 4; ++k) z_sh[irow * 4 + k][jcol] = zacc[k];
    __syncthreads();

    // ---------------- decoder: out_row = Wmap * (z^T q[pos]) + bmap -----
    for (int r = s; r < e; ++r) {
        const int pos = r - s;
        const int par = r & 1;
        float pd = 0.f;
        #pragma unroll
        for (int kk = 0; kk < 4; ++kk) {
            const int k = part * 4 + kk;
            pd += qsh[pos][k] * z_sh[k][w];
        }
        pd += __shfl_xor(pd, 1); pd += __shfl_xor(pd, 2); pd += __shfl_xor(pd, 4);
        if (part == 0) dec_sh[par][w] = pd;
        __syncthreads();
        float o = bm;
        #pragma unroll
        for (int v = 0; v < 32; ++v) o += wm[v] * dec_sh[par][v];
        out[(size_t)r * 256 + t] = o;
    }
}

extern "C" void kernel_launch(void* const* d_in, const int* in_sizes, int n_in,
                              void* d_out, int out_size, void* d_ws, size_t ws_size,
                              hipStream_t stream) {
    const float* x    = (const float*)d_in[0];
    const int*   batch= (const int*)  d_in[1];
    const float* Wk   = (const float*)d_in[2];
    const float* Wv   = (const float*)d_in[3];
    const float* Wq   = (const float*)d_in[4];
    const float* Wmap = (const float*)d_in[5];
    const float* bmap = (const float*)d_in[6];
    float* out = (float*)d_out;

    const int N = in_sizes[1];                 // 196608 rows
    float* pe    = (float*)((char*)d_ws + WS_PE);
    float* query = (float*)((char*)d_ws + WS_QUERY);
    int*   ptr   = (int*)  ((char*)d_ws + WS_PTR);
    float* out2  = out + (size_t)N * 256;      // output 1: batch echo as floats

    k_batch_ptr<<<(N + 255) / 256, 256, 0, stream>>>(batch, out2, ptr, N);
    k_pe<<<(MAXN * DIM) / 256, 256, 0, stream>>>(pe);
    k_query<<<(MAXN * WDIM) / 256, 256, 0, stream>>>(pe, Wq, query);
    k_main<<<N_SETS, 256, 0, stream>>>(x, Wk, Wv, Wmap, bmap, pe, query, ptr, out);
}

// Round 2
// 162.109 us; speedup vs baseline: 12.8364x; 12.8364x over previous
//
#include <hip/hip_runtime.h>
#include <math.h>

#define N_SETS 4096
#define MAXN   64
#define DIM    256
#define WDIM   32

typedef _Float16 f16;
typedef __attribute__((ext_vector_type(8))) _Float16 f16x8;
typedef __attribute__((ext_vector_type(4))) float     f32x4;

// ---------------- ws layout ----------------
#define WS_PE    0         // fp32 [64][256]  65536
#define WS_QH    65536     // f16  [64][32]   4096
#define WS_WKV   69632     // f16  [64][256]  32768  (rows 0-31 Wk, 32-63 Wv)
#define WS_WMAPH 102400    // f16  [256][32]  16384
#define WS_PEKV  118784    // fp32 [64][64]   16384  (cols 0-31 pe*Wk^T, 32-63 pe*Wv^T)
#define WS_PTR   135168    // int  [4097]

// Set-start detection + batch echo (output 1, written as float values)
__global__ void k_batch_ptr(const int* __restrict__ batch, float* __restrict__ out2,
                            int* __restrict__ ptr, int N) {
    int i = blockIdx.x * blockDim.x + threadIdx.x;
    if (i >= N) return;
    int b = batch[i];
    out2[i] = (float)b;
    if (i == 0 || batch[i - 1] != b) ptr[b] = i;
    if (i == N - 1) ptr[N_SETS] = N;
}

// sinusoid PE table [64][256] fp32
__global__ void k_pe(float* __restrict__ pe) {
    int idx = blockIdx.x * blockDim.x + threadIdx.x;   // 0..16383
    int p = idx >> 8, i = idx & 255;
    float e   = (float)(2 * (i / 2)) / 256.0f;
    float inv = powf(10000.0f, -e);
    float ang = (float)p * inv;
    pe[idx] = (i & 1) ? cosf(ang) : sinf(ang);
}

// convert weights to f16: wkv[64][256], wmaph[256][32]
__global__ void k_wcvt(const float* __restrict__ Wk, const float* __restrict__ Wv,
                       const float* __restrict__ Wmap, f16* __restrict__ wkv,
                       f16* __restrict__ wmaph) {
    int idx = blockIdx.x * blockDim.x + threadIdx.x;   // 0..24575
    if (idx < 16384) {
        int j = idx >> 8, d = idx & 255;
        float v = (j < 32) ? Wk[j * 256 + d] : Wv[(j - 32) * 256 + d];
        wkv[idx] = (f16)v;
    } else if (idx < 24576) {
        int i2 = idx - 16384;                           // [256][32] row-major = Wmap layout
        wmaph[i2] = (f16)Wmap[i2];
    }
}

// pekv[pos][j] fp32, qh[pos][k] f16
__global__ void k_prep(const float* __restrict__ pe, const float* __restrict__ Wk,
                       const float* __restrict__ Wv, const float* __restrict__ Wq,
                       float* __restrict__ pekv, f16* __restrict__ qh) {
    int idx = blockIdx.x * blockDim.x + threadIdx.x;   // 0..6143
    if (idx < 4096) {
        int pos = idx >> 6, j = idx & 63;
        const float* w  = (j < 32) ? (Wk + j * 256) : (Wv + (j - 32) * 256);
        const float* pr = pe + pos * 256;
        float s = 0.f;
        for (int d = 0; d < 256; d += 4) {
            float4 a = *(const float4*)(pr + d);
            float4 b = *(const float4*)(w + d);
            s += a.x * b.x + a.y * b.y + a.z * b.z + a.w * b.w;
        }
        pekv[idx] = s;
    } else if (idx < 6144) {
        int i2 = idx - 4096;
        int pos = i2 >> 5, k = i2 & 31;
        const float* pr = pe + pos * 256;
        const float* wr = Wq + k * 256;
        float s = 0.f;
        for (int d = 0; d < 256; d += 4) {
            float4 a = *(const float4*)(pr + d);
            float4 b = *(const float4*)(wr + d);
            s += a.x * b.x + a.y * b.y + a.z * b.z + a.w * b.w;
        }
        qh[i2] = (f16)s;
    }
}

// Fused per-set encoder+decoder with f16 MFMA. One block (4 waves) per set.
// LDS map (59392 B static):
//   [0, 32768)      xsh  f16 [64][256]  XOR-swizzled    | overlay after GEMM1:
//   [0, 20480)        wmh f16 [256][40] padded
//   [20480, 25600)    qsh f16 [64][40]  padded
//   [25600, 30720)    dsh f16 [64][40]  padded
//   [30720, 31744)    bsh f32 [256]
//   [32768, 49152)  wsh  f16 [32][256]  XOR-swizzled (Wk pass then Wv pass)
//   [49152, 57344)  ysh  f16 [64][64]
//   [57344, 59392)  zsh  f16 [32][32]
__global__ __launch_bounds__(256) void k_main(
        const float* __restrict__ x,     const f16* __restrict__ wkv,
        const f16* __restrict__ wmaph,   const f16* __restrict__ qh,
        const float* __restrict__ pekv,  const float* __restrict__ bmap,
        const int* __restrict__ ptr,     float* __restrict__ out) {
    __shared__ char lds[59392];
    f16*   ysh = (f16*)(lds + 49152);
    f16*   zsh = (f16*)(lds + 57344);
    float* bsh = (float*)(lds + 30720);

    const int b    = blockIdx.x;
    const int t    = threadIdx.x;
    const int wv   = t >> 6;
    const int lane = t & 63;
    const int l15  = lane & 15;
    const int lhi  = lane >> 4;          // 0..3
    const int s = ptr[b];
    const int n = ptr[b + 1] - s;        // 32 or 64

    // ---- stage x -> xsh (f16, swizzled), zero rows >= n ----
    #pragma unroll
    for (int p = 0; p < 8; ++p) {
        int c = t + 256 * p;
        int m = c >> 5, d0 = (c & 31) * 8;
        f16x8 h;
        if (m < n) {
            const float* xr = x + (size_t)(s + m) * 256 + d0;
            float4 a  = *(const float4*)xr;
            float4 a2 = *(const float4*)(xr + 4);
            h[0]=(f16)a.x;  h[1]=(f16)a.y;  h[2]=(f16)a.z;  h[3]=(f16)a.w;
            h[4]=(f16)a2.x; h[5]=(f16)a2.y; h[6]=(f16)a2.z; h[7]=(f16)a2.w;
        } else {
            #pragma unroll
            for (int ii = 0; ii < 8; ++ii) h[ii] = (f16)0.f;
        }
        *(f16x8*)(lds + ((m * 512 + d0 * 2) ^ ((m & 7) << 4))) = h;
    }

    // ---- GEMM1: Y = X*Wkv^T (+pekv), two 32-col passes ----
    for (int pass = 0; pass < 2; ++pass) {
        // stage 32 rows of Wkv -> wsh (swizzled)
        #pragma unroll
        for (int p = 0; p < 4; ++p) {
            int c = t + 256 * p;
            int j = c >> 5, d0 = (c & 31) * 8;
            f16x8 w8 = *(const f16x8*)(wkv + (pass * 32 + j) * 256 + d0);
            *(f16x8*)(lds + 32768 + ((j * 512 + d0 * 2) ^ ((j & 7) << 4))) = w8;
        }
        __syncthreads();

        f32x4 acc0 = {0.f,0.f,0.f,0.f}, acc1 = {0.f,0.f,0.f,0.f};
        const int m = 16 * wv + l15;
        #pragma unroll
        for (int ks = 0; ks < 8; ++ks) {
            int k0 = ks * 32 + lhi * 8;
            f16x8 a  = *(const f16x8*)(lds + ((m * 512 + k0 * 2) ^ ((m & 7) << 4)));
            f16x8 b0 = *(const f16x8*)(lds + 32768 + ((l15 * 512 + k0 * 2) ^ ((l15 & 7) << 4)));
            f16x8 b1 = *(const f16x8*)(lds + 32768 + (((16 + l15) * 512 + k0 * 2) ^ ((l15 & 7) << 4)));
            acc0 = __builtin_amdgcn_mfma_f32_16x16x32_f16(a, b0, acc0, 0, 0, 0);
            acc1 = __builtin_amdgcn_mfma_f32_16x16x32_f16(a, b1, acc1, 0, 0, 0);
        }
        // epilogue: + pekv, mask invalid rows, write f16 to ysh
        #pragma unroll
        for (int nt = 0; nt < 2; ++nt) {
            f32x4 A = nt ? acc1 : acc0;
            #pragma unroll
            for (int q = 0; q < 4; ++q) {
                int row = 16 * wv + lhi * 4 + q;
                int col = pass * 32 + 16 * nt + l15;
                float v = (row < n) ? (A[q] + pekv[row * 64 + col]) : 0.f;
                ysh[row * 64 + col] = (f16)v;
            }
        }
        __syncthreads();
    }

    // ---- GEMM2: Z = YV^T * YK  (+ overlay staging for decoder) ----
    // overlay staging (xsh region is dead now)
    #pragma unroll
    for (int p = 0; p < 4; ++p) {           // wmh [256][40]
        int c = t + 256 * p;
        int d = c >> 2, v0 = (c & 3) * 8;
        *(f16x8*)(lds + d * 80 + v0 * 2) = *(const f16x8*)(wmaph + d * 32 + v0);
    }
    {                                        // qsh [64][40]
        int m2 = t >> 2, v0 = (t & 3) * 8;
        *(f16x8*)(lds + 20480 + m2 * 80 + v0 * 2) = *(const f16x8*)(qh + m2 * 32 + v0);
    }
    bsh[t] = bmap[t];

    {
        int it = wv >> 1, jt = wv & 1;
        f32x4 zacc = {0.f,0.f,0.f,0.f};
        #pragma unroll
        for (int ks = 0; ks < 2; ++ks) {
            int r0 = ks * 32 + lhi * 8;
            f16x8 av, bk;
            #pragma unroll
            for (int ii = 0; ii < 8; ++ii) {
                av[ii] = ysh[(r0 + ii) * 64 + 32 + 16 * it + l15];
                bk[ii] = ysh[(r0 + ii) * 64 + 16 * jt + l15];
            }
            zacc = __builtin_amdgcn_mfma_f32_16x16x32_f16(av, bk, zacc, 0, 0, 0);
        }
        #pragma unroll
        for (int q = 0; q < 4; ++q)
            zsh[(16 * it + lhi * 4 + q) * 32 + 16 * jt + l15] = (f16)zacc[q];
    }
    __syncthreads();

    // ---- GEMM3: dec = query * Z ----
    {
        int k0 = lhi * 8;
        f16x8 aq = *(const f16x8*)(lds + 20480 + (16 * wv + l15) * 80 + k0 * 2);
        f16x8 bz0, bz1;
        #pragma unroll
        for (int ii = 0; ii < 8; ++ii) {
            bz0[ii] = zsh[(k0 + ii) * 32 + l15];
            bz1[ii] = zsh[(k0 + ii) * 32 + 16 + l15];
        }
        f32x4 d0 = {0.f,0.f,0.f,0.f}, d1 = {0.f,0.f,0.f,0.f};
        d0 = __builtin_amdgcn_mfma_f32_16x16x32_f16(aq, bz0, d0, 0, 0, 0);
        d1 = __builtin_amdgcn_mfma_f32_16x16x32_f16(aq, bz1, d1, 0, 0, 0);
        #pragma unroll
        for (int q = 0; q < 4; ++q) {
            int row = 16 * wv + lhi * 4 + q;
            *(f16*)(lds + 25600 + row * 80 + l15 * 2)        = (f16)d0[q];
            *(f16*)(lds + 25600 + row * 80 + (16 + l15) * 2) = (f16)d1[q];
        }
    }
    __syncthreads();

    // ---- GEMM4: out = dec * Wmap^T + bmap ----
    {
        int k0 = lhi * 8;
        f16x8 ad = *(const f16x8*)(lds + 25600 + (16 * wv + l15) * 80 + k0 * 2);
        #pragma unroll
        for (int nt = 0; nt < 16; ++nt) {
            f16x8 bw = *(const f16x8*)(lds + (16 * nt + l15) * 80 + k0 * 2);
            f32x4 o = {0.f,0.f,0.f,0.f};
            o = __builtin_amdgcn_mfma_f32_16x16x32_f16(ad, bw, o, 0, 0, 0);
            #pragma unroll
            for (int q = 0; q < 4; ++q) {
                int row = 16 * wv + lhi * 4 + q;
                if (row < n) {
                    int d = 16 * nt + l15;
                    out[(size_t)(s + row) * 256 + d] = o[q] + bsh[d];
                }
            }
        }
    }
}

extern "C" void kernel_launch(void* const* d_in, const int* in_sizes, int n_in,
                              void* d_out, int out_size, void* d_ws, size_t ws_size,
                              hipStream_t stream) {
    const float* x    = (const float*)d_in[0];
    const int*   batch= (const int*)  d_in[1];
    const float* Wk   = (const float*)d_in[2];
    const float* Wv   = (const float*)d_in[3];
    const float* Wq   = (const float*)d_in[4];
    const float* Wmap = (const float*)d_in[5];
    const float* bmap = (const float*)d_in[6];
    float* out = (float*)d_out;

    const int N = in_sizes[1];                 // 196608 rows
    float* pe    = (float*)((char*)d_ws + WS_PE);
    f16*   qh    = (f16*)  ((char*)d_ws + WS_QH);
    f16*   wkv   = (f16*)  ((char*)d_ws + WS_WKV);
    f16*   wmaph = (f16*)  ((char*)d_ws + WS_WMAPH);
    float* pekv  = (float*)((char*)d_ws + WS_PEKV);
    int*   ptr   = (int*)  ((char*)d_ws + WS_PTR);
    float* out2  = out + (size_t)N * 256;      // output 1: batch echo as floats

    k_batch_ptr<<<(N + 255) / 256, 256, 0, stream>>>(batch, out2, ptr, N);
    k_pe<<<(MAXN * DIM) / 256, 256, 0, stream>>>(pe);
    k_wcvt<<<96, 256, 0, stream>>>(Wk, Wv, Wmap, wkv, wmaph);
    k_prep<<<24, 256, 0, stream>>>(pe, Wk, Wv, Wq, pekv, qh);
    k_main<<<N_SETS, 256, 0, stream>>>(x, wkv, wmaph, qh, pekv, bmap, ptr, out);
}

// Round 3
// 125.439 us; speedup vs baseline: 16.5890x; 1.2923x over previous
//
#include <hip/hip_runtime.h>
#include <math.h>

#define N_SETS 4096

typedef _Float16 f16;
typedef __attribute__((ext_vector_type(8))) _Float16 f16x8;
typedef __attribute__((ext_vector_type(4))) _Float16 f16x4;
typedef __attribute__((ext_vector_type(4))) float     f32x4;

// ---------------- ws layout ----------------
#define WS_PE    0         // fp32 [64][256]  65536
#define WS_QH    65536     // f16  [64][32]   4096
#define WS_WKV   69632     // f16  [64][256]  32768  (rows 0-31 Wk, 32-63 Wv)
#define WS_WMAPH 102400    // f16  [256][32]  16384
#define WS_PEKV  118784    // fp32 [64][64]   16384
#define WS_PTR   135168    // int  [4097]

// aux1: blocks [0,768) -> batch_ptr + out2 echo; blocks [768,832) -> pe table
__global__ void k_aux1(const int* __restrict__ batch, float* __restrict__ out2,
                       int* __restrict__ ptr, int N, float* __restrict__ pe) {
    int blk = blockIdx.x;
    if (blk < 768) {
        int i = blk * 256 + threadIdx.x;
        if (i >= N) return;
        int b = batch[i];
        out2[i] = (float)b;
        if (i == 0 || batch[i - 1] != b) ptr[b] = i;
        if (i == N - 1) ptr[N_SETS] = N;
    } else {
        int idx = (blk - 768) * 256 + threadIdx.x;   // 0..16383
        int p = idx >> 8, i = idx & 255;
        float e   = (float)(2 * (i / 2)) / 256.0f;
        float inv = powf(10000.0f, -e);
        float ang = (float)p * inv;
        pe[idx] = (i & 1) ? cosf(ang) : sinf(ang);
    }
}

// aux2: blocks [0,96) -> weight f16 convert; blocks [96,120) -> pekv + qh
__global__ void k_aux2(const float* __restrict__ Wk, const float* __restrict__ Wv,
                       const float* __restrict__ Wq, const float* __restrict__ Wmap,
                       const float* __restrict__ pe, f16* __restrict__ wkv,
                       f16* __restrict__ wmaph, float* __restrict__ pekv,
                       f16* __restrict__ qh) {
    int blk = blockIdx.x;
    if (blk < 96) {
        int idx = blk * 256 + threadIdx.x;           // 0..24575
        if (idx < 16384) {
            int j = idx >> 8, d = idx & 255;
            float v = (j < 32) ? Wk[j * 256 + d] : Wv[(j - 32) * 256 + d];
            wkv[idx] = (f16)v;
        } else {
            int i2 = idx - 16384;
            wmaph[i2] = (f16)Wmap[i2];
        }
    } else {
        int idx = (blk - 96) * 256 + threadIdx.x;    // 0..6143
        if (idx < 4096) {
            int pos = idx >> 6, j = idx & 63;
            const float* w  = (j < 32) ? (Wk + j * 256) : (Wv + (j - 32) * 256);
            const float* pr = pe + pos * 256;
            float s = 0.f;
            for (int d = 0; d < 256; d += 4) {
                float4 a = *(const float4*)(pr + d);
                float4 b = *(const float4*)(w + d);
                s += a.x * b.x + a.y * b.y + a.z * b.z + a.w * b.w;
            }
            pekv[idx] = s;
        } else if (idx < 6144) {
            int i2 = idx - 4096;
            int pos = i2 >> 5, k = i2 & 31;
            const float* pr = pe + pos * 256;
            const float* wr = Wq + k * 256;
            float s = 0.f;
            for (int d = 0; d < 256; d += 4) {
                float4 a = *(const float4*)(pr + d);
                float4 b = *(const float4*)(wr + d);
                s += a.x * b.x + a.y * b.y + a.z * b.z + a.w * b.w;
            }
            qh[i2] = (f16)s;
        }
    }
}

// Fused per-set encoder+decoder, f16 MFMA. One 4-wave block per set.
// LDS map (31744 B -> 5 blocks/CU possible, >=4 guaranteed):
//   [0,     16384)  W region: wsh f16 [32][256] swz ((r&7)<<4)  | later wmh f16 [256][32] swz ((d&7)<<4)
//   [16384, 24576)  yshT f16 [64c][64r] swz ((c&7)<<4)          | later dsh f16 [64m][32v] swz ((m&7)<<4)
//   [24576, 28672)  qsh  f16 [64][32]  swz ((m&7)<<4)
//   [28672, 30720)  zT   f16 [32c][32r] swz ((c&3)<<4)
//   [30720, 31744)  bsh  f32 [256]
__global__ __launch_bounds__(256, 4) void k_main(
        const float* __restrict__ x,     const f16* __restrict__ wkv,
        const f16* __restrict__ wmaph,   const f16* __restrict__ qh,
        const float* __restrict__ pekv,  const float* __restrict__ bmap,
        const int* __restrict__ ptr,     float* __restrict__ out) {
    __shared__ char lds[31744];
    float* bsh = (float*)(lds + 30720);

    const int b    = blockIdx.x;
    const int t    = threadIdx.x;
    const int wv   = t >> 6;
    const int l15  = t & 15;
    const int lhi  = (t & 63) >> 4;       // 0..3
    const int s = ptr[b];
    const int n = ptr[b + 1] - s;         // 32 or 64

    // ---- stage qsh ----
    {
        int m = t >> 2, v0 = (t & 3) * 8;
        f16x8 q8 = *(const f16x8*)(qh + m * 32 + v0);
        *(f16x8*)(lds + 24576 + ((m * 64 + v0 * 2) ^ ((m & 7) << 4))) = q8;
    }
    bsh[t] = bmap[t];
    // ---- stage wsh = Wk rows ----
    #pragma unroll
    for (int i2 = 0; i2 < 4; ++i2) {
        int c = t + 256 * i2;
        int j = c >> 5, d0 = (c & 31) * 8;
        f16x8 w8 = *(const f16x8*)(wkv + j * 256 + d0);
        *(f16x8*)(lds + ((j * 512 + d0 * 2) ^ ((j & 7) << 4))) = w8;
    }
    // ---- A-fragment straight from global into registers (f16), reused for both passes ----
    f16x8 areg[8];
    {
        const int arow = 16 * wv + l15;
        if (arow < n) {
            const float* xr = x + (size_t)(s + arow) * 256 + lhi * 8;
            #pragma unroll
            for (int ks = 0; ks < 8; ++ks) {
                float4 a  = *(const float4*)(xr + ks * 32);
                float4 a2 = *(const float4*)(xr + ks * 32 + 4);
                f16x8 h;
                h[0]=(f16)a.x;  h[1]=(f16)a.y;  h[2]=(f16)a.z;  h[3]=(f16)a.w;
                h[4]=(f16)a2.x; h[5]=(f16)a2.y; h[6]=(f16)a2.z; h[7]=(f16)a2.w;
                areg[ks] = h;
            }
        } else {
            #pragma unroll
            for (int ks = 0; ks < 8; ++ks) {
                f16x8 h;
                #pragma unroll
                for (int ii = 0; ii < 8; ++ii) h[ii] = (f16)0.f;
                areg[ks] = h;
            }
        }
    }
    __syncthreads();

    // ---- GEMM1: Y = X*Wkv^T + pekv, two 32-col passes, output to yshT (transposed) ----
    #pragma unroll
    for (int pass = 0; pass < 2; ++pass) {
        f32x4 acc0 = {0.f,0.f,0.f,0.f}, acc1 = {0.f,0.f,0.f,0.f};
        if (16 * wv < n) {
            #pragma unroll
            for (int ks = 0; ks < 8; ++ks) {
                const int off = ks * 64 + lhi * 16;
                f16x8 b0 = *(const f16x8*)(lds + ((l15 * 512 + off) ^ ((l15 & 7) << 4)));
                f16x8 b1 = *(const f16x8*)(lds + (((16 + l15) * 512 + off) ^ ((l15 & 7) << 4)));
                acc0 = __builtin_amdgcn_mfma_f32_16x16x32_f16(areg[ks], b0, acc0, 0, 0, 0);
                acc1 = __builtin_amdgcn_mfma_f32_16x16x32_f16(areg[ks], b1, acc1, 0, 0, 0);
            }
        }
        const int row0 = 16 * wv + lhi * 4;
        #pragma unroll
        for (int nt = 0; nt < 2; ++nt) {
            const f32x4 A = nt ? acc1 : acc0;
            const int col = pass * 32 + 16 * nt + l15;
            f16x4 h4;
            #pragma unroll
            for (int q = 0; q < 4; ++q) {
                const int row = row0 + q;
                const float v = (row < n) ? (A[q] + pekv[row * 64 + col]) : 0.f;
                h4[q] = (f16)v;
            }
            *(f16x4*)(lds + 16384 + ((col * 128 + row0 * 2) ^ ((col & 7) << 4))) = h4;
        }
        __syncthreads();
        if (pass == 0) {   // stage wsh = Wv rows
            #pragma unroll
            for (int i2 = 0; i2 < 4; ++i2) {
                int c = t + 256 * i2;
                int j = c >> 5, d0 = (c & 31) * 8;
                f16x8 w8 = *(const f16x8*)(wkv + (32 + j) * 256 + d0);
                *(f16x8*)(lds + ((j * 512 + d0 * 2) ^ ((j & 7) << 4))) = w8;
            }
            __syncthreads();
        }
    }

    // ---- GEMM2: Z = YV^T * YK -> zT; stage wmh over dead W region ----
    {
        const int it = wv >> 1, jt = wv & 1;
        f32x4 zacc = {0.f,0.f,0.f,0.f};
        const int nks = (n + 31) >> 5;
        for (int ks = 0; ks < nks; ++ks) {
            const int r2 = ks * 64 + lhi * 16;
            f16x8 av = *(const f16x8*)(lds + 16384 + (((32 + 16 * it + l15) * 128 + r2) ^ ((l15 & 7) << 4)));
            f16x8 bk = *(const f16x8*)(lds + 16384 + (((16 * jt + l15) * 128 + r2) ^ ((l15 & 7) << 4)));
            zacc = __builtin_amdgcn_mfma_f32_16x16x32_f16(av, bk, zacc, 0, 0, 0);
        }
        #pragma unroll
        for (int i2 = 0; i2 < 4; ++i2) {   // stage wmh
            int c = t + 256 * i2;
            int d = c >> 2, v0 = (c & 3) * 8;
            f16x8 w8 = *(const f16x8*)(wmaph + d * 32 + v0);
            *(f16x8*)(lds + ((d * 64 + v0 * 2) ^ ((d & 7) << 4))) = w8;
        }
        const int zc = 16 * jt + l15, zr0 = 16 * it + lhi * 4;
        f16x4 h4;
        #pragma unroll
        for (int q = 0; q < 4; ++q) h4[q] = (f16)zacc[q];
        *(f16x4*)(lds + 28672 + ((zc * 64 + zr0 * 2) ^ ((zc & 3) << 4))) = h4;
    }
    __syncthreads();

    // ---- GEMM3: dec = query * Z -> dsh (over dead yshT region) ----
    if (16 * wv < n) {
        const int k2 = lhi * 16;
        f16x8 aq  = *(const f16x8*)(lds + 24576 + (((16 * wv + l15) * 64 + k2) ^ ((l15 & 7) << 4)));
        f16x8 bz0 = *(const f16x8*)(lds + 28672 + ((l15 * 64 + k2) ^ ((l15 & 3) << 4)));
        f16x8 bz1 = *(const f16x8*)(lds + 28672 + (((16 + l15) * 64 + k2) ^ ((l15 & 3) << 4)));
        f32x4 dd0 = {0.f,0.f,0.f,0.f}, dd1 = {0.f,0.f,0.f,0.f};
        dd0 = __builtin_amdgcn_mfma_f32_16x16x32_f16(aq, bz0, dd0, 0, 0, 0);
        dd1 = __builtin_amdgcn_mfma_f32_16x16x32_f16(aq, bz1, dd1, 0, 0, 0);
        #pragma unroll
        for (int q = 0; q < 4; ++q) {
            const int m = 16 * wv + lhi * 4 + q;
            *(f16*)(lds + 16384 + ((m * 64 + l15 * 2) ^ ((m & 7) << 4)))      = (f16)dd0[q];
            *(f16*)(lds + 16384 + ((m * 64 + 32 + l15 * 2) ^ ((m & 7) << 4))) = (f16)dd1[q];
        }
    }
    __syncthreads();

    // ---- GEMM4: out = dec * Wmap^T + bmap ----
    if (16 * wv < n) {
        const int k2 = lhi * 16;
        f16x8 ad = *(const f16x8*)(lds + 16384 + (((16 * wv + l15) * 64 + k2) ^ ((l15 & 7) << 4)));
        const int row0 = 16 * wv + lhi * 4;
        float* orow = out + (size_t)s * 256;
        #pragma unroll
        for (int nt = 0; nt < 16; ++nt) {
            const int dcol = 16 * nt + l15;
            f16x8 bw = *(const f16x8*)(lds + ((dcol * 64 + k2) ^ ((l15 & 7) << 4)));
            f32x4 o = {0.f,0.f,0.f,0.f};
            o = __builtin_amdgcn_mfma_f32_16x16x32_f16(ad, bw, o, 0, 0, 0);
            const float bb = bsh[dcol];
            #pragma unroll
            for (int q = 0; q < 4; ++q) {
                const int row = row0 + q;
                if (row < n) orow[(size_t)row * 256 + dcol] = o[q] + bb;
            }
        }
    }
}

extern "C" void kernel_launch(void* const* d_in, const int* in_sizes, int n_in,
                              void* d_out, int out_size, void* d_ws, size_t ws_size,
                              hipStream_t stream) {
    const float* x    = (const float*)d_in[0];
    const int*   batch= (const int*)  d_in[1];
    const float* Wk   = (const float*)d_in[2];
    const float* Wv   = (const float*)d_in[3];
    const float* Wq   = (const float*)d_in[4];
    const float* Wmap = (const float*)d_in[5];
    const float* bmap = (const float*)d_in[6];
    float* out = (float*)d_out;

    const int N = in_sizes[1];                 // 196608 rows
    float* pe    = (float*)((char*)d_ws + WS_PE);
    f16*   qh    = (f16*)  ((char*)d_ws + WS_QH);
    f16*   wkv   = (f16*)  ((char*)d_ws + WS_WKV);
    f16*   wmaph = (f16*)  ((char*)d_ws + WS_WMAPH);
    float* pekv  = (float*)((char*)d_ws + WS_PEKV);
    int*   ptr   = (int*)  ((char*)d_ws + WS_PTR);
    float* out2  = out + (size_t)N * 256;      // output 1: batch echo as floats

    k_aux1<<<832, 256, 0, stream>>>(batch, out2, ptr, N, pe);
    k_aux2<<<120, 256, 0, stream>>>(Wk, Wv, Wq, Wmap, pe, wkv, wmaph, pekv, qh);
    k_main<<<N_SETS, 256, 0, stream>>>(x, wkv, wmaph, qh, pekv, bmap, ptr, out);
}

// Round 4
// 115.157 us; speedup vs baseline: 18.0700x; 1.0893x over previous
//
#include <hip/hip_runtime.h>
#include <math.h>

#define N_SETS 4096
#define SETS_PER_BLOCK 8
#define GRID_MAIN (N_SETS / SETS_PER_BLOCK)

typedef _Float16 f16;
typedef __attribute__((ext_vector_type(8))) _Float16 f16x8;
typedef __attribute__((ext_vector_type(4))) _Float16 f16x4;
typedef __attribute__((ext_vector_type(4))) float     f32x4;

// ---------------- ws layout ----------------
#define WS_PE    0         // fp32 [64][256]  65536
#define WS_QH    65536     // f16  [64][32]   4096
#define WS_WKV   69632     // f16  [64][256]  32768  (rows 0-31 Wk, 32-63 Wv)
#define WS_WMAPH 102400    // f16  [256][32]  16384
#define WS_PEH   118784    // f16  [64][256]  32768
#define WS_PTR   151552    // int  [4097]

// aux1: blocks [0,768) -> batch_ptr + out2 echo; blocks [768,832) -> pe table
__global__ void k_aux1(const int* __restrict__ batch, float* __restrict__ out2,
                       int* __restrict__ ptr, int N, float* __restrict__ pe) {
    int blk = blockIdx.x;
    if (blk < 768) {
        int i = blk * 256 + threadIdx.x;
        if (i >= N) return;
        int b = batch[i];
        out2[i] = (float)b;
        if (i == 0 || batch[i - 1] != b) ptr[b] = i;
        if (i == N - 1) ptr[N_SETS] = N;
    } else {
        int idx = (blk - 768) * 256 + threadIdx.x;   // 0..16383
        int p = idx >> 8, i = idx & 255;
        float e   = (float)(2 * (i / 2)) / 256.0f;
        float inv = powf(10000.0f, -e);
        float ang = (float)p * inv;
        pe[idx] = (i & 1) ? cosf(ang) : sinf(ang);
    }
}

// aux2: [0,96) weight f16 convert; [96,160) peh convert; [160,168) qh
__global__ void k_aux2(const float* __restrict__ Wk, const float* __restrict__ Wv,
                       const float* __restrict__ Wq, const float* __restrict__ Wmap,
                       const float* __restrict__ pe, f16* __restrict__ wkv,
                       f16* __restrict__ wmaph, f16* __restrict__ peh,
                       f16* __restrict__ qh) {
    int blk = blockIdx.x;
    if (blk < 96) {
        int idx = blk * 256 + threadIdx.x;           // 0..24575
        if (idx < 16384) {
            int j = idx >> 8, d = idx & 255;
            float v = (j < 32) ? Wk[j * 256 + d] : Wv[(j - 32) * 256 + d];
            wkv[idx] = (f16)v;
        } else {
            int i2 = idx - 16384;
            wmaph[i2] = (f16)Wmap[i2];
        }
    } else if (blk < 160) {
        int idx = (blk - 96) * 256 + threadIdx.x;    // 0..16383
        peh[idx] = (f16)pe[idx];
    } else {
        int idx = (blk - 160) * 256 + threadIdx.x;   // 0..2047
        int pos = idx >> 5, k = idx & 31;
        const float* pr = pe + pos * 256;
        const float* wr = Wq + k * 256;
        float s = 0.f;
        for (int d = 0; d < 256; d += 4) {
            float4 a = *(const float4*)(pr + d);
            float4 b = *(const float4*)(wr + d);
            s += a.x * b.x + a.y * b.y + a.z * b.z + a.w * b.w;
        }
        qh[idx] = (f16)s;
    }
}

// Fused encoder+decoder, 8 sets per block, weights staged once.
// LDS map (59392 B, 2 blocks/CU, all 512 blocks resident):
//   [0,     32768)  wsh f16 [64][256]  swz ((j&7)<<4)   (Wk rows 0-31, Wv 32-63)
//   [32768, 49152)  wmh f16 [256][32]  swz ((d&7)<<4)
//   [49152, 57344)  yshT f16 [64c][64r] swz ((c&7)<<4)  | dsh f16 [64m][32v] swz ((m&7)<<4)
//   [57344, 59392)  zT  f16 [32c][32r] swz ((c&3)<<4)
__global__ __launch_bounds__(256, 2) void k_main(
        const float* __restrict__ x,     const f16* __restrict__ wkv,
        const f16* __restrict__ wmaph,   const f16* __restrict__ qh,
        const f16* __restrict__ peh,     const float* __restrict__ bmap,
        const int* __restrict__ ptr,     float* __restrict__ out) {
    __shared__ char lds[59392];

    const int t    = threadIdx.x;
    const int wv   = t >> 6;
    const int l15  = t & 15;
    const int lhi  = (t & 63) >> 4;       // 0..3
    const int arow = 16 * wv + l15;

    int pv[SETS_PER_BLOCK + 1];
    #pragma unroll
    for (int i = 0; i <= SETS_PER_BLOCK; ++i)
        pv[i] = ptr[blockIdx.x * SETS_PER_BLOCK + i];

    // ---- stage wsh (Wk|Wv) once ----
    #pragma unroll
    for (int i2 = 0; i2 < 8; ++i2) {
        int c = t + 256 * i2;
        int j = c >> 5, d0 = (c & 31) * 8;
        f16x8 w8 = *(const f16x8*)(wkv + j * 256 + d0);
        *(f16x8*)(lds + ((j * 512 + d0 * 2) ^ ((j & 7) << 4))) = w8;
    }
    // ---- stage wmh once ----
    #pragma unroll
    for (int i2 = 0; i2 < 4; ++i2) {
        int c = t + 256 * i2;
        int d = c >> 2, v0 = (c & 3) * 8;
        f16x8 w8 = *(const f16x8*)(wmaph + d * 32 + v0);
        *(f16x8*)(lds + 32768 + ((d * 64 + v0 * 2) ^ ((d & 7) << 4))) = w8;
    }
    // ---- per-lane constants (set-invariant) ----
    f16x8 pef[8];
    #pragma unroll
    for (int ks = 0; ks < 8; ++ks)
        pef[ks] = *(const f16x8*)(peh + arow * 256 + ks * 32 + lhi * 8);
    const f16x8 qreg = *(const f16x8*)(qh + arow * 32 + lhi * 8);
    float bm[16];
    #pragma unroll
    for (int nt = 0; nt < 16; ++nt) bm[nt] = bmap[16 * nt + l15];

    // ---- prefetch x rows of set 0 ----
    float4 xf[16];
    {
        const int s0 = pv[0], n0 = pv[1] - pv[0];
        if (arow < n0) {
            const float* xr = x + (size_t)(s0 + arow) * 256 + lhi * 8;
            #pragma unroll
            for (int ks = 0; ks < 8; ++ks) {
                xf[2 * ks]     = *(const float4*)(xr + ks * 32);
                xf[2 * ks + 1] = *(const float4*)(xr + ks * 32 + 4);
            }
        }
    }
    __syncthreads();

    for (int si = 0; si < SETS_PER_BLOCK; ++si) {
        const int s = pv[si], n = pv[si + 1] - s;
        const int n32 = (n + 31) & ~31;

        // convert current x + PE -> areg (f16)
        f16x8 areg[8];
        if (arow < n) {
            #pragma unroll
            for (int ks = 0; ks < 8; ++ks) {
                float4 a = xf[2 * ks], a2 = xf[2 * ks + 1];
                f16x8 h;
                h[0]=(f16)a.x;  h[1]=(f16)a.y;  h[2]=(f16)a.z;  h[3]=(f16)a.w;
                h[4]=(f16)a2.x; h[5]=(f16)a2.y; h[6]=(f16)a2.z; h[7]=(f16)a2.w;
                areg[ks] = h + pef[ks];
            }
        } else {
            #pragma unroll
            for (int ks = 0; ks < 8; ++ks) {
                f16x8 h;
                #pragma unroll
                for (int ii = 0; ii < 8; ++ii) h[ii] = (f16)0.f;
                areg[ks] = h;
            }
        }
        // prefetch next set's x (overlaps GEMM1..4)
        if (si + 1 < SETS_PER_BLOCK) {
            const int s1 = pv[si + 1], n1 = pv[si + 2] - pv[si + 1];
            if (arow < n1) {
                const float* xr = x + (size_t)(s1 + arow) * 256 + lhi * 8;
                #pragma unroll
                for (int ks = 0; ks < 8; ++ks) {
                    xf[2 * ks]     = *(const float4*)(xr + ks * 32);
                    xf[2 * ks + 1] = *(const float4*)(xr + ks * 32 + 4);
                }
            }
        }

        // ---- GEMM1: Y = (X+PE)*Wkv^T -> yshT (transposed) ----
        if (16 * wv < n32) {
            f32x4 acc[4];
            #pragma unroll
            for (int nt = 0; nt < 4; ++nt) acc[nt] = (f32x4){0.f, 0.f, 0.f, 0.f};
            #pragma unroll
            for (int ks = 0; ks < 8; ++ks) {
                #pragma unroll
                for (int nt = 0; nt < 4; ++nt) {
                    f16x8 bf = *(const f16x8*)(lds +
                        (((16 * nt + l15) * 512 + ks * 64 + lhi * 16) ^ ((l15 & 7) << 4)));
                    acc[nt] = __builtin_amdgcn_mfma_f32_16x16x32_f16(areg[ks], bf, acc[nt], 0, 0, 0);
                }
            }
            const int row0 = 16 * wv + lhi * 4;
            #pragma unroll
            for (int nt = 0; nt < 4; ++nt) {
                const int col = 16 * nt + l15;
                f16x4 h4;
                #pragma unroll
                for (int q = 0; q < 4; ++q) h4[q] = (f16)acc[nt][q];
                *(f16x4*)(lds + 49152 + ((col * 128 + row0 * 2) ^ ((col & 7) << 4))) = h4;
            }
        }
        __syncthreads();

        // ---- GEMM2: Z = YV^T * YK -> zT ----
        {
            const int it = wv >> 1, jt = wv & 1;
            f32x4 zacc = {0.f, 0.f, 0.f, 0.f};
            const int nks = n32 >> 5;
            for (int ks = 0; ks < nks; ++ks) {
                const int r2 = ks * 64 + lhi * 16;
                f16x8 av = *(const f16x8*)(lds + 49152 +
                    (((32 + 16 * it + l15) * 128 + r2) ^ ((l15 & 7) << 4)));
                f16x8 bk = *(const f16x8*)(lds + 49152 +
                    (((16 * jt + l15) * 128 + r2) ^ ((l15 & 7) << 4)));
                zacc = __builtin_amdgcn_mfma_f32_16x16x32_f16(av, bk, zacc, 0, 0, 0);
            }
            const int zc = 16 * jt + l15, zr0 = 16 * it + lhi * 4;
            f16x4 h4;
            #pragma unroll
            for (int q = 0; q < 4; ++q) h4[q] = (f16)zacc[q];
            *(f16x4*)(lds + 57344 + ((zc * 64 + zr0 * 2) ^ ((zc & 3) << 4))) = h4;
        }
        __syncthreads();

        // ---- GEMM3: dec = query * Z -> dsh (overlay yshT) ----
        if (16 * wv < n) {
            const int k2 = lhi * 16;
            f16x8 bz0 = *(const f16x8*)(lds + 57344 + ((l15 * 64 + k2) ^ ((l15 & 3) << 4)));
            f16x8 bz1 = *(const f16x8*)(lds + 57344 + (((16 + l15) * 64 + k2) ^ ((l15 & 3) << 4)));
            f32x4 dd0 = {0.f, 0.f, 0.f, 0.f}, dd1 = {0.f, 0.f, 0.f, 0.f};
            dd0 = __builtin_amdgcn_mfma_f32_16x16x32_f16(qreg, bz0, dd0, 0, 0, 0);
            dd1 = __builtin_amdgcn_mfma_f32_16x16x32_f16(qreg, bz1, dd1, 0, 0, 0);
            #pragma unroll
            for (int q = 0; q < 4; ++q) {
                const int m = 16 * wv + lhi * 4 + q;
                *(f16*)(lds + 49152 + ((m * 64 + l15 * 2) ^ ((m & 7) << 4)))            = (f16)dd0[q];
                *(f16*)(lds + 49152 + ((m * 64 + (16 + l15) * 2) ^ ((m & 7) << 4)))     = (f16)dd1[q];
            }
        }
        __syncthreads();

        // ---- GEMM4: out = dec * Wmap^T + bmap ----
        if (16 * wv < n) {
            const int k2 = lhi * 16;
            f16x8 ad = *(const f16x8*)(lds + 49152 +
                (((16 * wv + l15) * 64 + k2) ^ ((l15 & 7) << 4)));
            const int row0 = 16 * wv + lhi * 4;
            float* orow = out + (size_t)s * 256;
            #pragma unroll
            for (int nt = 0; nt < 16; ++nt) {
                const int dcol = 16 * nt + l15;
                f16x8 bw = *(const f16x8*)(lds + 32768 + ((dcol * 64 + k2) ^ ((l15 & 7) << 4)));
                f32x4 o = {0.f, 0.f, 0.f, 0.f};
                o = __builtin_amdgcn_mfma_f32_16x16x32_f16(ad, bw, o, 0, 0, 0);
                #pragma unroll
                for (int q = 0; q < 4; ++q) {
                    const int row = row0 + q;
                    if (row < n) orow[(size_t)row * 256 + dcol] = o[q] + bm[nt];
                }
            }
        }
        __syncthreads();
    }
}

extern "C" void kernel_launch(void* const* d_in, const int* in_sizes, int n_in,
                              void* d_out, int out_size, void* d_ws, size_t ws_size,
                              hipStream_t stream) {
    const float* x    = (const float*)d_in[0];
    const int*   batch= (const int*)  d_in[1];
    const float* Wk   = (const float*)d_in[2];
    const float* Wv   = (const float*)d_in[3];
    const float* Wq   = (const float*)d_in[4];
    const float* Wmap = (const float*)d_in[5];
    const float* bmap = (const float*)d_in[6];
    float* out = (float*)d_out;

    const int N = in_sizes[1];                 // 196608 rows
    float* pe    = (float*)((char*)d_ws + WS_PE);
    f16*   qh    = (f16*)  ((char*)d_ws + WS_QH);
    f16*   wkv   = (f16*)  ((char*)d_ws + WS_WKV);
    f16*   wmaph = (f16*)  ((char*)d_ws + WS_WMAPH);
    f16*   peh   = (f16*)  ((char*)d_ws + WS_PEH);
    int*   ptr   = (int*)  ((char*)d_ws + WS_PTR);
    float* out2  = out + (size_t)N * 256;      // output 1: batch echo as floats

    k_aux1<<<832, 256, 0, stream>>>(batch, out2, ptr, N, pe);
    k_aux2<<<168, 256, 0, stream>>>(Wk, Wv, Wq, Wmap, pe, wkv, wmaph, peh, qh);
    k_main<<<GRID_MAIN, 256, 0, stream>>>(x, wkv, wmaph, qh, peh, bmap, ptr, out);
}